// Round 2
// baseline (226.302 us; speedup 1.0000x reference)
//
#include <hip/hip_runtime.h>
#include <hip/hip_bf16.h>

#define NN_ 8192
#define DD_ 128
#define NSPLIT 16
#define JSPLIT (NN_ / NSPLIT)  // 512

typedef short bf16x8 __attribute__((ext_vector_type(8)));
typedef float f32x4 __attribute__((ext_vector_type(4)));

union U4 { uint4 u; bf16x8 h; };

#if __has_builtin(__builtin_amdgcn_exp2f)
#define EXP2(x) __builtin_amdgcn_exp2f(x)
#else
#define EXP2(x) __expf((x) * 0.69314718056f)
#endif

#define C1 115.415603f  /* 80*log2(e) */
#define C2 96.9491065f  /* 67.2*log2(e) */
#define LN2 0.69314718056f

__device__ __forceinline__ unsigned short f2bf(float f) {
    unsigned int u = __float_as_uint(f);
    unsigned int r = (u + 0x7FFFu + ((u >> 16) & 1u)) >> 16;  // RNE
    return (unsigned short)r;
}

// ---------------- kernel 1: L2-normalize rows -> bf16, class histogram ----------
// 256 threads = 4 waves; one row per 16-lane group -> 16 rows/block, 512 blocks.
__global__ __launch_bounds__(256) void k_norm(const float* __restrict__ x,
                                              const int* __restrict__ labels,
                                              unsigned short* __restrict__ ebf,
                                              int* __restrict__ hist) {
    int t = threadIdx.x;
    int row = blockIdx.x * 16 + (t >> 4);
    int g = t & 15;
    const float4* xr = (const float4*)(x + (size_t)row * DD_);
    float4 v0 = xr[g * 2];
    float4 v1 = xr[g * 2 + 1];
    float ss = v0.x * v0.x + v0.y * v0.y + v0.z * v0.z + v0.w * v0.w +
               v1.x * v1.x + v1.y * v1.y + v1.z * v1.z + v1.w * v1.w;
#pragma unroll
    for (int m = 1; m < 16; m <<= 1) ss += __shfl_xor(ss, m);
    float inv = 1.0f / fmaxf(sqrtf(ss), 1e-12f);
    float vs[8] = {v0.x, v0.y, v0.z, v0.w, v1.x, v1.y, v1.z, v1.w};
    unsigned int p[4];
#pragma unroll
    for (int k = 0; k < 4; k++) {
        unsigned short lo = f2bf(vs[2 * k] * inv);
        unsigned short hi = f2bf(vs[2 * k + 1] * inv);
        p[k] = (unsigned int)lo | ((unsigned int)hi << 16);
    }
    uint4 out = {p[0], p[1], p[2], p[3]};
    ((uint4*)ebf)[row * 16 + g] = out;
    if (g == 0) atomicAdd(&hist[labels[row]], 1);
}

// ---------------- kernel 2: main sim + masked LSE pass --------------------------
// grid (NSPLIT, NN_/128), block 512 (8 waves). Wave w owns rows
// blockIdx.y*128 + w*16 .. +15 ; scans j in [jsplit*512, +512) in steps of 16.
// __launch_bounds__(512,8): 8 waves/SIMD -> 32 waves/CU (4 blocks/CU), VGPR<=64.
__global__ __launch_bounds__(512, 8) void k_main(const unsigned short* __restrict__ ebf,
                                                 const int* __restrict__ labels,
                                                 float* __restrict__ states) {
    const int lane = threadIdx.x & 63;
    const int wave = threadIdx.x >> 6;
    const int quad = lane >> 4;
    const int lcol = lane & 15;
    const int rowbase = blockIdx.y * 128 + wave * 16;
    const int jsplit = blockIdx.x;
    const int j0 = jsplit * JSPLIT, j1 = j0 + JSPLIT;

    const uint4* eb4 = (const uint4*)ebf;  // 16B units; row stride = 16 units

    // A fragments: resident for the whole kernel. A[m=lane&15][k=quad*8+j]
    U4 afr[4];
    int arow = rowbase + lcol;
#pragma unroll
    for (int kc = 0; kc < 4; kc++) afr[kc].u = eb4[arow * 16 + kc * 4 + quad];

    int il[4];
#pragma unroll
    for (int r = 0; r < 4; r++) il[r] = labels[rowbase + quad * 4 + r];

    float S_an[4] = {0.f, 0.f, 0.f, 0.f};
    float m_p[4] = {-1e30f, -1e30f, -1e30f, -1e30f};  // in log2 units
    float s_p[4] = {0.f, 0.f, 0.f, 0.f};

    U4 bfr[4];
#pragma unroll
    for (int kc = 0; kc < 4; kc++) bfr[kc].u = eb4[(j0 + lcol) * 16 + kc * 4 + quad];

    for (int jt = j0; jt < j1; jt += 16) {
        // prefetch next B tile (always-valid address)
        int jn = (jt + 16 < j1) ? (jt + 16) : j0;
        U4 bnx[4];
#pragma unroll
        for (int kc = 0; kc < 4; kc++) bnx[kc].u = eb4[(jn + lcol) * 16 + kc * 4 + quad];

        f32x4 acc = {0.f, 0.f, 0.f, 0.f};
#pragma unroll
        for (int kc = 0; kc < 4; kc++)
            acc = __builtin_amdgcn_mfma_f32_16x16x32_bf16(afr[kc].h, bfr[kc].h, acc, 0, 0, 0);

        int j = jt + lcol;
        int jl = labels[j];
#pragma unroll
        for (int r = 0; r < 4; r++) {
            float s = acc[r];
            int i = rowbase + quad * 4 + r;
            bool same = (jl == il[r]);
            // negatives: exp2((an_term - 67.2)*log2e), fixed shift (max of term)
            float u = s + 0.4f;
            float a = fmaxf(u, 0.0f);
            float t2 = fmaf(a * C1, u - 0.8f, -C2);
            float e = EXP2(t2);
            S_an[r] += same ? 0.0f : e;
            // positives (rare): ap_term*log2e, online LSE in log2 space
            if (same && j != i) {
                float al = fmaxf(1.4f - s, 0.0f) * (-C1);
                float tp = al * (s - 0.6f);
                float mn = fmaxf(m_p[r], tp);
                s_p[r] = s_p[r] * EXP2(m_p[r] - mn) + EXP2(tp - mn);
                m_p[r] = mn;
            }
        }
#pragma unroll
        for (int kc = 0; kc < 4; kc++) bfr[kc] = bnx[kc];
    }

    // merge the 16 column-stripes of each row (lanes sharing quad)
#pragma unroll
    for (int r = 0; r < 4; r++) {
#pragma unroll
        for (int m = 1; m < 16; m <<= 1) {
            S_an[r] += __shfl_xor(S_an[r], m);
            float m2 = __shfl_xor(m_p[r], m);
            float s2 = __shfl_xor(s_p[r], m);
            float mn = fmaxf(m_p[r], m2);
            s_p[r] = s_p[r] * EXP2(m_p[r] - mn) + s2 * EXP2(m2 - mn);
            m_p[r] = mn;
        }
    }
    if (lcol == 0) {
#pragma unroll
        for (int r = 0; r < 4; r++) {
            int i = rowbase + quad * 4 + r;
            float* st = states + ((size_t)i * NSPLIT + jsplit) * 3;
            st[0] = m_p[r];
            st[1] = s_p[r];
            st[2] = S_an[r];
        }
    }
}

// ---------------- kernel 3: merge splits, per-row loss, block reduce ------------
__global__ __launch_bounds__(256) void k_fin(const float* __restrict__ states,
                                             const int* __restrict__ labels,
                                             const int* __restrict__ hist,
                                             float* __restrict__ accum) {
    int i = blockIdx.x * 256 + threadIdx.x;
    int cnt = hist[labels[i]];
    int np = cnt - 1, nn = NN_ - cnt;
    float m_p = -1e30f, s_p = 0.f, S_an = 0.f;
#pragma unroll
    for (int k = 0; k < NSPLIT; k++) {
        const float* st = states + ((size_t)i * NSPLIT + k) * 3;
        float m2 = st[0], s2 = st[1];
        S_an += st[2];
        float mn = fmaxf(m_p, m2);
        s_p = s_p * EXP2(m_p - mn) + s2 * EXP2(m2 - mn);
        m_p = mn;
    }
    float loss = 0.0f, v = 0.0f;
    if (np > 0 && nn > 0 && s_p > 0.f && S_an > 0.f) {
        float lse_p = LN2 * m_p + __logf(s_p);
        float lse_n = 67.2f + __logf(S_an);
        float z = lse_p + lse_n + __logf((float)np) + __logf((float)nn);
        loss = fmaxf(z, 0.0f) + log1pf(__expf(-fabsf(z)));  // softplus, stable
        v = 1.0f;
    }
#pragma unroll
    for (int m = 1; m < 64; m <<= 1) {
        loss += __shfl_xor(loss, m);
        v += __shfl_xor(v, m);
    }
    if ((threadIdx.x & 63) == 0) {
        atomicAdd(&accum[0], loss);
        atomicAdd(&accum[1], v);
    }
}

__global__ void k_div(const float* __restrict__ accum, float* __restrict__ out) {
    if (threadIdx.x == 0) out[0] = accum[0] / fmaxf(accum[1], 1.0f);
}

// ---------------- launch --------------------------------------------------------
extern "C" void kernel_launch(void* const* d_in, const int* in_sizes, int n_in,
                              void* d_out, int out_size, void* d_ws, size_t ws_size,
                              hipStream_t stream) {
    const float* embeds = (const float*)d_in[0];
    const int* labels = (const int*)d_in[1];
    float* out = (float*)d_out;

    char* ws = (char*)d_ws;
    unsigned short* ebf = (unsigned short*)ws;                 // 2,097,152 B
    float* states = (float*)(ws + 2097152);                    // 8192*16*3*4 = 1,572,864 B
    int* hist = (int*)(ws + 2097152 + 1572864);                // 2048 B
    float* accum = (float*)(ws + 2097152 + 1572864 + 2048);    // 8 B

    hipMemsetAsync(hist, 0, 2048 + 8, stream);  // zero hist + accum (contiguous)

    k_norm<<<NN_ / 16, 256, 0, stream>>>(embeds, labels, ebf, hist);
    k_main<<<dim3(NSPLIT, NN_ / 128), 512, 0, stream>>>(ebf, labels, states);
    k_fin<<<NN_ / 256, 256, 0, stream>>>(states, labels, hist, accum);
    k_div<<<1, 64, 0, stream>>>(accum, out);
}

// Round 3
// 193.046 us; speedup vs baseline: 1.1723x; 1.1723x over previous
//
#include <hip/hip_runtime.h>
#include <hip/hip_bf16.h>

#define NN_ 8192
#define DD_ 128
#define NSPLIT 8
#define JSPLIT (NN_ / NSPLIT)  // 1024

typedef short bf16x8 __attribute__((ext_vector_type(8)));
typedef float f32x4 __attribute__((ext_vector_type(4)));

union U4 { uint4 u; bf16x8 h; };

#if __has_builtin(__builtin_amdgcn_exp2f)
#define EXP2(x) __builtin_amdgcn_exp2f(x)
#else
#define EXP2(x) __expf((x) * 0.69314718056f)
#endif

#define C1 115.415603f  /* 80*log2(e) */
#define C2 96.9491065f  /* 67.2*log2(e) */
#define LN2 0.69314718056f

__device__ __forceinline__ unsigned short f2bf(float f) {
    unsigned int u = __float_as_uint(f);
    unsigned int r = (u + 0x7FFFu + ((u >> 16) & 1u)) >> 16;  // RNE
    return (unsigned short)r;
}

// ---------------- kernel 1: L2-normalize rows -> bf16, class histogram ----------
// 256 threads = 4 waves; one row per 16-lane group -> 16 rows/block, 512 blocks.
__global__ __launch_bounds__(256) void k_norm(const float* __restrict__ x,
                                              const int* __restrict__ labels,
                                              unsigned short* __restrict__ ebf,
                                              int* __restrict__ hist) {
    int t = threadIdx.x;
    int row = blockIdx.x * 16 + (t >> 4);
    int g = t & 15;
    const float4* xr = (const float4*)(x + (size_t)row * DD_);
    float4 v0 = xr[g * 2];
    float4 v1 = xr[g * 2 + 1];
    float ss = v0.x * v0.x + v0.y * v0.y + v0.z * v0.z + v0.w * v0.w +
               v1.x * v1.x + v1.y * v1.y + v1.z * v1.z + v1.w * v1.w;
#pragma unroll
    for (int m = 1; m < 16; m <<= 1) ss += __shfl_xor(ss, m);
    float inv = 1.0f / fmaxf(sqrtf(ss), 1e-12f);
    float vs[8] = {v0.x, v0.y, v0.z, v0.w, v1.x, v1.y, v1.z, v1.w};
    unsigned int p[4];
#pragma unroll
    for (int k = 0; k < 4; k++) {
        unsigned short lo = f2bf(vs[2 * k] * inv);
        unsigned short hi = f2bf(vs[2 * k + 1] * inv);
        p[k] = (unsigned int)lo | ((unsigned int)hi << 16);
    }
    uint4 out = {p[0], p[1], p[2], p[3]};
    ((uint4*)ebf)[row * 16 + g] = out;
    if (g == 0) atomicAdd(&hist[labels[row]], 1);
}

// ---------------- kernel 2: main sim + masked LSE pass --------------------------
// grid (NSPLIT, NN_/128), block 512 (8 waves). Wave w owns rows
// blockIdx.y*128 + w*16 .. +15 ; scans j in [jsplit*1024, +1024) in steps of 16.
// __launch_bounds__(512,4): VGPR cap 128 — fits ~100 live regs, NO SPILLS.
// (R2's (512,8) capped at 64 VGPR -> scratch spills -> 2 GB L2 traffic, 162 us.)
__global__ __launch_bounds__(512, 4) void k_main(const unsigned short* __restrict__ ebf,
                                                 const int* __restrict__ labels,
                                                 float* __restrict__ states) {
    const int lane = threadIdx.x & 63;
    const int wave = threadIdx.x >> 6;
    const int quad = lane >> 4;
    const int lcol = lane & 15;
    const int rowbase = blockIdx.y * 128 + wave * 16;
    const int jsplit = blockIdx.x;
    const int j0 = jsplit * JSPLIT, j1 = j0 + JSPLIT;

    const uint4* eb4 = (const uint4*)ebf;  // 16B units; row stride = 16 units

    // A fragments: resident for the whole kernel. A[m=lane&15][k=quad*8+j]
    U4 afr[4];
    int arow = rowbase + lcol;
#pragma unroll
    for (int kc = 0; kc < 4; kc++) afr[kc].u = eb4[arow * 16 + kc * 4 + quad];

    int il[4];
#pragma unroll
    for (int r = 0; r < 4; r++) il[r] = labels[rowbase + quad * 4 + r];

    float S_an[4] = {0.f, 0.f, 0.f, 0.f};
    float m_p[4] = {-1e30f, -1e30f, -1e30f, -1e30f};  // in log2 units
    float s_p[4] = {0.f, 0.f, 0.f, 0.f};

    U4 bfr[4];
#pragma unroll
    for (int kc = 0; kc < 4; kc++) bfr[kc].u = eb4[(j0 + lcol) * 16 + kc * 4 + quad];
    int jl = labels[j0 + lcol];

    for (int jt = j0; jt < j1; jt += 16) {
        // prefetch next B tile + labels (always-valid address)
        int jn = (jt + 16 < j1) ? (jt + 16) : j0;
        U4 bnx[4];
#pragma unroll
        for (int kc = 0; kc < 4; kc++) bnx[kc].u = eb4[(jn + lcol) * 16 + kc * 4 + quad];
        int jln = labels[jn + lcol];

        f32x4 acc = {0.f, 0.f, 0.f, 0.f};
#pragma unroll
        for (int kc = 0; kc < 4; kc++)
            acc = __builtin_amdgcn_mfma_f32_16x16x32_bf16(afr[kc].h, bfr[kc].h, acc, 0, 0, 0);

        int j = jt + lcol;
#pragma unroll
        for (int r = 0; r < 4; r++) {
            float s = acc[r];
            int i = rowbase + quad * 4 + r;
            bool same = (jl == il[r]);
            // negatives: exp2((an_term - 67.2)*log2e), fixed shift (max of term)
            float u = s + 0.4f;
            float a = fmaxf(u, 0.0f);
            float t2 = fmaf(a * C1, u - 0.8f, -C2);
            float e = EXP2(t2);
            S_an[r] += same ? 0.0f : e;
            // positives (rare): ap_term*log2e, online LSE in log2 space
            if (same && j != i) {
                float al = fmaxf(1.4f - s, 0.0f) * (-C1);
                float tp = al * (s - 0.6f);
                float mn = fmaxf(m_p[r], tp);
                s_p[r] = s_p[r] * EXP2(m_p[r] - mn) + EXP2(tp - mn);
                m_p[r] = mn;
            }
        }
#pragma unroll
        for (int kc = 0; kc < 4; kc++) bfr[kc] = bnx[kc];
        jl = jln;
    }

    // merge the 16 column-stripes of each row (lanes sharing quad)
#pragma unroll
    for (int r = 0; r < 4; r++) {
#pragma unroll
        for (int m = 1; m < 16; m <<= 1) {
            S_an[r] += __shfl_xor(S_an[r], m);
            float m2 = __shfl_xor(m_p[r], m);
            float s2 = __shfl_xor(s_p[r], m);
            float mn = fmaxf(m_p[r], m2);
            s_p[r] = s_p[r] * EXP2(m_p[r] - mn) + s2 * EXP2(m2 - mn);
            m_p[r] = mn;
        }
    }
    if (lcol == 0) {
#pragma unroll
        for (int r = 0; r < 4; r++) {
            int i = rowbase + quad * 4 + r;
            float* st = states + ((size_t)i * NSPLIT + jsplit) * 3;
            st[0] = m_p[r];
            st[1] = s_p[r];
            st[2] = S_an[r];
        }
    }
}

// ---------------- kernel 3: merge splits, per-row loss, block reduce ------------
__global__ __launch_bounds__(256) void k_fin(const float* __restrict__ states,
                                             const int* __restrict__ labels,
                                             const int* __restrict__ hist,
                                             float* __restrict__ accum) {
    int i = blockIdx.x * 256 + threadIdx.x;
    int cnt = hist[labels[i]];
    int np = cnt - 1, nn = NN_ - cnt;
    float m_p = -1e30f, s_p = 0.f, S_an = 0.f;
#pragma unroll
    for (int k = 0; k < NSPLIT; k++) {
        const float* st = states + ((size_t)i * NSPLIT + k) * 3;
        float m2 = st[0], s2 = st[1];
        S_an += st[2];
        float mn = fmaxf(m_p, m2);
        s_p = s_p * EXP2(m_p - mn) + s2 * EXP2(m2 - mn);
        m_p = mn;
    }
    float loss = 0.0f, v = 0.0f;
    if (np > 0 && nn > 0 && s_p > 0.f && S_an > 0.f) {
        float lse_p = LN2 * m_p + __logf(s_p);
        float lse_n = 67.2f + __logf(S_an);
        float z = lse_p + lse_n + __logf((float)np) + __logf((float)nn);
        loss = fmaxf(z, 0.0f) + log1pf(__expf(-fabsf(z)));  // softplus, stable
        v = 1.0f;
    }
#pragma unroll
    for (int m = 1; m < 64; m <<= 1) {
        loss += __shfl_xor(loss, m);
        v += __shfl_xor(v, m);
    }
    if ((threadIdx.x & 63) == 0) {
        atomicAdd(&accum[0], loss);
        atomicAdd(&accum[1], v);
    }
}

__global__ void k_div(const float* __restrict__ accum, float* __restrict__ out) {
    if (threadIdx.x == 0) out[0] = accum[0] / fmaxf(accum[1], 1.0f);
}

// ---------------- launch --------------------------------------------------------
extern "C" void kernel_launch(void* const* d_in, const int* in_sizes, int n_in,
                              void* d_out, int out_size, void* d_ws, size_t ws_size,
                              hipStream_t stream) {
    const float* embeds = (const float*)d_in[0];
    const int* labels = (const int*)d_in[1];
    float* out = (float*)d_out;

    char* ws = (char*)d_ws;
    unsigned short* ebf = (unsigned short*)ws;                 // 2,097,152 B
    float* states = (float*)(ws + 2097152);                    // 8192*8*3*4 = 786,432 B
    int* hist = (int*)(ws + 2097152 + 786432);                 // 2048 B
    float* accum = (float*)(ws + 2097152 + 786432 + 2048);     // 8 B

    hipMemsetAsync(hist, 0, 2048 + 8, stream);  // zero hist + accum (contiguous)

    k_norm<<<NN_ / 16, 256, 0, stream>>>(embeds, labels, ebf, hist);
    k_main<<<dim3(NSPLIT, NN_ / 128), 512, 0, stream>>>(ebf, labels, states);
    k_fin<<<NN_ / 256, 256, 0, stream>>>(states, labels, hist, accum);
    k_div<<<1, 64, 0, stream>>>(accum, out);
}

// Round 4
// 103.671 us; speedup vs baseline: 2.1829x; 1.8621x over previous
//
#include <hip/hip_runtime.h>
#include <hip/hip_bf16.h>

#define NN_ 8192
#define DD_ 128
#define NSPLIT 8
#define JSPLIT (NN_ / NSPLIT)  // 1024

typedef short bf16x8 __attribute__((ext_vector_type(8)));
typedef float f32x4 __attribute__((ext_vector_type(4)));

union U4 { uint4 u; bf16x8 h; };

#if __has_builtin(__builtin_amdgcn_exp2f)
#define EXP2(x) __builtin_amdgcn_exp2f(x)
#else
#define EXP2(x) __expf((x) * 0.69314718056f)
#endif

#define C1 115.415603f  /* 80*log2(e) */
#define C2 96.9491065f  /* 67.2*log2(e) */
#define LN2 0.69314718056f

__device__ __forceinline__ unsigned short f2bf(float f) {
    unsigned int u = __float_as_uint(f);
    unsigned int r = (u + 0x7FFFu + ((u >> 16) & 1u)) >> 16;  // RNE
    return (unsigned short)r;
}

// Fragment-swizzled layout (uint4 units): fb[grp*256 + chunk*16 + row16]
//   grp = row>>4, row16 = row&15, chunk = element_block (8 bf16 = 16B) in [0,16).
// MFMA frag load for K-block kc then reads fb[grp*256 + kc*64 + lane]:
//   chunk = kc*4 + (lane>>4), row16 = lane&15  -> contiguous 1KB per wave. [R3 fix]

// ---------------- kernel 1: L2-normalize rows -> bf16 (swizzled) ----------------
// 256 threads = 4 waves; 16-lane group per row -> 16 rows (one grp) per block.
__global__ __launch_bounds__(256) void k_norm(const float* __restrict__ x,
                                              unsigned short* __restrict__ ebf) {
    int t = threadIdx.x;
    int r16 = t >> 4;  // row within group
    int g = t & 15;    // chunk
    int row = blockIdx.x * 16 + r16;
    const float4* xr = (const float4*)(x + (size_t)row * DD_);
    float4 v0 = xr[g * 2];
    float4 v1 = xr[g * 2 + 1];
    float ss = v0.x * v0.x + v0.y * v0.y + v0.z * v0.z + v0.w * v0.w +
               v1.x * v1.x + v1.y * v1.y + v1.z * v1.z + v1.w * v1.w;
    // reduce over the 16 lanes of this row's group (stride 16 in thread id = same wave)
#pragma unroll
    for (int m = 16; m < 256; m <<= 1) {
        // threads of one row are t = r16 + 16*g; xor on bits >= 4 stays within row group
    }
    // simpler: rows are laid out so that the 16 threads of a row have consecutive
    // (t>>4)?? no — threads of row r16 are t = r16*16..r16*16+15 (g = t&15). Reduce over low 4 bits:
#pragma unroll
    for (int m = 1; m < 16; m <<= 1) ss += __shfl_xor(ss, m);
    float inv = 1.0f / fmaxf(sqrtf(ss), 1e-12f);
    float vs[8] = {v0.x, v0.y, v0.z, v0.w, v1.x, v1.y, v1.z, v1.w};
    unsigned int p[4];
#pragma unroll
    for (int k = 0; k < 4; k++) {
        unsigned short lo = f2bf(vs[2 * k] * inv);
        unsigned short hi = f2bf(vs[2 * k + 1] * inv);
        p[k] = (unsigned int)lo | ((unsigned int)hi << 16);
    }
    uint4 out = {p[0], p[1], p[2], p[3]};
    ((uint4*)ebf)[blockIdx.x * 256 + g * 16 + r16] = out;  // swizzled store
}

// ---------------- kernel 2: main sim + masked LSE pass --------------------------
// grid (NSPLIT, 64), block 512 (8 waves). Wave owns 16 rows; scans JSPLIT cols.
__global__ __launch_bounds__(512, 4) void k_main(const unsigned short* __restrict__ ebf,
                                                 const int* __restrict__ labels,
                                                 float* __restrict__ states) {
    const int lane = threadIdx.x & 63;
    const int wave = threadIdx.x >> 6;
    const int quad = lane >> 4;
    const int lcol = lane & 15;
    const int rowbase = blockIdx.y * 128 + wave * 16;
    const int jsplit = blockIdx.x;
    const int j0 = jsplit * JSPLIT, j1 = j0 + JSPLIT;

    const uint4* fb = (const uint4*)ebf;

    // A fragments: resident for the whole kernel (coalesced loads)
    U4 afr[4];
#pragma unroll
    for (int kc = 0; kc < 4; kc++) afr[kc].u = fb[(rowbase >> 4) * 256 + kc * 64 + lane];

    int il[4];
#pragma unroll
    for (int r = 0; r < 4; r++) il[r] = labels[rowbase + quad * 4 + r];

    float S_an[4] = {0.f, 0.f, 0.f, 0.f};
    float m_p[4] = {-1e30f, -1e30f, -1e30f, -1e30f};  // log2 units
    float s_p[4] = {0.f, 0.f, 0.f, 0.f};
    float cnt[4] = {0.f, 0.f, 0.f, 0.f};  // same-label count (incl self)

    // two-stage rotation double buffer (no copies)
    U4 b0[4], b1[4];
#pragma unroll
    for (int kc = 0; kc < 4; kc++) b0[kc].u = fb[(j0 >> 4) * 256 + kc * 64 + lane];
    int jl0 = labels[j0 + lcol];
#pragma unroll
    for (int kc = 0; kc < 4; kc++) b1[kc].u = fb[((j0 + 16) >> 4) * 256 + kc * 64 + lane];
    int jl1 = labels[j0 + 16 + lcol];

    const int NIT = JSPLIT / 32;
    for (int it = 0; it < NIT; ++it) {
        const int jt = j0 + it * 32;
        const int jp = (it + 1 < NIT) ? jt + 32 : j0;  // prefetch target (wrap ok)

        // ---- tile 0: columns jt..jt+15, fragments in b0 ----
        {
            f32x4 acc = {0.f, 0.f, 0.f, 0.f};
#pragma unroll
            for (int kc = 0; kc < 4; kc++)
                acc = __builtin_amdgcn_mfma_f32_16x16x32_bf16(afr[kc].h, b0[kc].h, acc, 0, 0, 0);
            int j = jt + lcol;
#pragma unroll
            for (int r = 0; r < 4; r++) {
                float s = acc[r];
                int i = rowbase + quad * 4 + r;
                bool same = (jl0 == il[r]);
                float u = s + 0.4f;
                float a = fmaxf(u, 0.0f);
                float t2 = fmaf(a * C1, u - 0.8f, -C2);
                float e = EXP2(t2);
                S_an[r] += same ? 0.0f : e;
                cnt[r] += same ? 1.0f : 0.0f;
                if (same && j != i) {
                    float al = fmaxf(1.4f - s, 0.0f) * (-C1);
                    float tp = al * (s - 0.6f);
                    float mn = fmaxf(m_p[r], tp);
                    s_p[r] = s_p[r] * EXP2(m_p[r] - mn) + EXP2(tp - mn);
                    m_p[r] = mn;
                }
            }
        }
        // refill b0 for next iteration's tile 0 (latency covered by tile-1 work)
#pragma unroll
        for (int kc = 0; kc < 4; kc++) b0[kc].u = fb[(jp >> 4) * 256 + kc * 64 + lane];
        int jl0n = labels[jp + lcol];

        // ---- tile 1: columns jt+16..jt+31, fragments in b1 ----
        {
            f32x4 acc = {0.f, 0.f, 0.f, 0.f};
#pragma unroll
            for (int kc = 0; kc < 4; kc++)
                acc = __builtin_amdgcn_mfma_f32_16x16x32_bf16(afr[kc].h, b1[kc].h, acc, 0, 0, 0);
            int j = jt + 16 + lcol;
#pragma unroll
            for (int r = 0; r < 4; r++) {
                float s = acc[r];
                int i = rowbase + quad * 4 + r;
                bool same = (jl1 == il[r]);
                float u = s + 0.4f;
                float a = fmaxf(u, 0.0f);
                float t2 = fmaf(a * C1, u - 0.8f, -C2);
                float e = EXP2(t2);
                S_an[r] += same ? 0.0f : e;
                cnt[r] += same ? 1.0f : 0.0f;
                if (same && j != i) {
                    float al = fmaxf(1.4f - s, 0.0f) * (-C1);
                    float tp = al * (s - 0.6f);
                    float mn = fmaxf(m_p[r], tp);
                    s_p[r] = s_p[r] * EXP2(m_p[r] - mn) + EXP2(tp - mn);
                    m_p[r] = mn;
                }
            }
        }
#pragma unroll
        for (int kc = 0; kc < 4; kc++) b1[kc].u = fb[((jp + 16) >> 4) * 256 + kc * 64 + lane];
        int jl1n = labels[jp + 16 + lcol];

        jl0 = jl0n;
        jl1 = jl1n;
    }

    // merge the 16 column-stripes of each row (lanes sharing quad)
#pragma unroll
    for (int r = 0; r < 4; r++) {
#pragma unroll
        for (int m = 1; m < 16; m <<= 1) {
            S_an[r] += __shfl_xor(S_an[r], m);
            cnt[r] += __shfl_xor(cnt[r], m);
            float m2 = __shfl_xor(m_p[r], m);
            float s2 = __shfl_xor(s_p[r], m);
            float mn = fmaxf(m_p[r], m2);
            s_p[r] = s_p[r] * EXP2(m_p[r] - mn) + s2 * EXP2(m2 - mn);
            m_p[r] = mn;
        }
    }
    if (lcol == 0) {
#pragma unroll
        for (int r = 0; r < 4; r++) {
            int i = rowbase + quad * 4 + r;
            float4 st = {m_p[r], s_p[r], S_an[r], cnt[r]};
            ((float4*)states)[(size_t)i * NSPLIT + jsplit] = st;
        }
    }
}

// ---------------- kernel 3: merge splits, per-row loss, per-wave partials -------
__global__ __launch_bounds__(256) void k_fin(const float* __restrict__ states,
                                             float* __restrict__ partials) {
    int i = blockIdx.x * 256 + threadIdx.x;
    float m_p = -1e30f, s_p = 0.f, S_an = 0.f, cnt = 0.f;
#pragma unroll
    for (int k = 0; k < NSPLIT; k++) {
        float4 st = ((const float4*)states)[(size_t)i * NSPLIT + k];
        S_an += st.z;
        cnt += st.w;
        float mn = fmaxf(m_p, st.x);
        s_p = s_p * EXP2(m_p - mn) + st.y * EXP2(st.x - mn);
        m_p = mn;
    }
    int np = (int)cnt - 1;
    int nn = NN_ - (int)cnt;
    float loss = 0.0f, v = 0.0f;
    if (np > 0 && nn > 0 && s_p > 0.f && S_an > 0.f) {
        float lse_p = LN2 * m_p + __logf(s_p);
        float lse_n = 67.2f + __logf(S_an);
        float z = lse_p + lse_n + __logf((float)np) + __logf((float)nn);
        loss = fmaxf(z, 0.0f) + log1pf(__expf(-fabsf(z)));  // stable softplus
        v = 1.0f;
    }
#pragma unroll
    for (int m = 1; m < 64; m <<= 1) {
        loss += __shfl_xor(loss, m);
        v += __shfl_xor(v, m);
    }
    if ((threadIdx.x & 63) == 0) {
        int w = (blockIdx.x << 2) | (threadIdx.x >> 6);  // global wave id, 128 total
        partials[w * 2] = loss;
        partials[w * 2 + 1] = v;
    }
}

// ---------------- kernel 4: final reduce over 128 wave-partials -----------------
__global__ void k_div(const float* __restrict__ partials, float* __restrict__ out) {
    int t = threadIdx.x;  // 64 threads
    float loss = partials[t * 2] + partials[(t + 64) * 2];
    float v = partials[t * 2 + 1] + partials[(t + 64) * 2 + 1];
#pragma unroll
    for (int m = 1; m < 64; m <<= 1) {
        loss += __shfl_xor(loss, m);
        v += __shfl_xor(v, m);
    }
    if (t == 0) out[0] = loss / fmaxf(v, 1.0f);
}

// ---------------- launch --------------------------------------------------------
extern "C" void kernel_launch(void* const* d_in, const int* in_sizes, int n_in,
                              void* d_out, int out_size, void* d_ws, size_t ws_size,
                              hipStream_t stream) {
    const float* embeds = (const float*)d_in[0];
    const int* labels = (const int*)d_in[1];
    float* out = (float*)d_out;

    char* ws = (char*)d_ws;
    unsigned short* ebf = (unsigned short*)ws;               // 2,097,152 B
    float* states = (float*)(ws + 2097152);                  // 8192*8*4*4 = 1,048,576 B
    float* partials = (float*)(ws + 2097152 + 1048576);      // 128*2*4 = 1024 B

    k_norm<<<NN_ / 16, 256, 0, stream>>>(embeds, ebf);
    k_main<<<dim3(NSPLIT, NN_ / 128), 512, 0, stream>>>(ebf, labels, states);
    k_fin<<<NN_ / 256, 256, 0, stream>>>(states, partials);
    k_div<<<1, 64, 0, stream>>>(partials, out);
}